// Round 13
// baseline (479.393 us; speedup 1.0000x reference)
//
#include <hip/hip_runtime.h>

// Problem constants
#define S_LEN 256
#define B_SZ  128
#define M_ROWS (S_LEN * B_SZ)          // 32768

typedef __attribute__((ext_vector_type(8))) short bf16x8;
typedef __attribute__((ext_vector_type(4))) float f32x4;

__device__ __forceinline__ unsigned short f2bf(float x) {
    unsigned u = __float_as_uint(x);
    unsigned r = (u + 0x7fffu + ((u >> 16) & 1u)) >> 16;   // RNE
    return (unsigned short)r;
}

__device__ __forceinline__ void gl_lds16(const void* g, void* l) {
    __builtin_amdgcn_global_load_lds(
        (const __attribute__((address_space(1))) unsigned int*)g,
        (__attribute__((address_space(3))) unsigned int*)l,
        16, 0, 0);
}

// ---------------- Pass 1: seq f32 -> bf16 ----------------
__global__ __launch_bounds__(256) void convert_seq(const float* __restrict__ in,
                                                   unsigned short* __restrict__ out,
                                                   long n4) {
    long i = (long)blockIdx.x * blockDim.x + threadIdx.x;
    long stride = (long)gridDim.x * blockDim.x;
    for (; i < n4; i += stride) {
        float4 v = ((const float4*)in)[i];
        ushort4 o;
        o.x = f2bf(v.x); o.y = f2bf(v.y); o.z = f2bf(v.z); o.w = f2bf(v.w);
        ((ushort4*)out)[i] = o;
    }
}

// ---------------- Pass 2: f1,f2 f32 -> bf16 (layer-major) ----------------
__global__ __launch_bounds__(256) void convert_f(const float* __restrict__ f1,
                                                 const float* __restrict__ f2,
                                                 unsigned short* __restrict__ out) {
    int g = blockIdx.x * 256 + threadIdx.x;            // 0..65535 float4 groups
    float4 v = (g < 32768) ? ((const float4*)f1)[g] : ((const float4*)f2)[g - 32768];
    ushort4 o;
    o.x = f2bf(v.x); o.y = f2bf(v.y); o.z = f2bf(v.z); o.w = f2bf(v.w);
    ((ushort4*)out)[g] = o;
}

// ---------------- Pass 3: W [2048][1024] f32 -> Wt [2][1024][2048] bf16 ----------------
__global__ __launch_bounds__(256) void transpose_w(const float* __restrict__ W11,
                                                   const float* __restrict__ W12,
                                                   unsigned short* __restrict__ Wt) {
    const int nt = blockIdx.x, kt = blockIdx.y, layer = blockIdx.z;
    const float* W = layer ? W12 : W11;
    __shared__ float T[64][65];
    const int c = threadIdx.x & 63, r4 = threadIdx.x >> 6;
    const int k0 = kt * 64, n0 = nt * 64;
    #pragma unroll
    for (int p = 0; p < 16; ++p) {
        int r = p * 4 + r4;
        T[r][c] = W[(size_t)(k0 + r) * 1024 + n0 + c];
    }
    __syncthreads();
    unsigned short* Wl = Wt + (size_t)layer * 1024 * 2048;
    #pragma unroll
    for (int p = 0; p < 16; ++p) {
        int n = p * 4 + r4;
        Wl[(size_t)(n0 + n) * 2048 + k0 + c] = f2bf(T[c][n]);
    }
}

// ---------------- Pass 4: c[layer][b][h] = f@W[1024:] + bias  (MFMA 128x128 tile) ----------------
__global__ __launch_bounds__(256) void c_precompute(const unsigned short* __restrict__ fbf, // [2][128][1024]
                                                    const unsigned short* __restrict__ Wt,  // [2][1024][2048]
                                                    const float* __restrict__ b11,
                                                    const float* __restrict__ b12,
                                                    float* __restrict__ cbuf) {            // [2][128][1024]
    __shared__ char smem[32768];
    unsigned short* ldsA = (unsigned short*)smem;            // [128][64]
    unsigned short* ldsB = (unsigned short*)(smem + 16384);  // [128][64]
    const int n0 = blockIdx.x * 128;
    const int layer = blockIdx.y;
    const int tid = threadIdx.x;
    const int w = tid >> 6, l = tid & 63;
    const int wm = w >> 1, wn = w & 1;
    const int lr = l & 15, lg = l >> 4;
    const unsigned short* Af = fbf + (size_t)layer * 128 * 1024;
    const unsigned short* Wl = Wt + (size_t)layer * 1024 * 2048;
    const float* bias = layer ? b12 : b11;

    f32x4 acc[4][4];
    #pragma unroll
    for (int i = 0; i < 4; ++i)
        #pragma unroll
        for (int j = 0; j < 4; ++j)
            #pragma unroll
            for (int e = 0; e < 4; ++e) acc[i][j][e] = 0.f;

    for (int kk = 0; kk < 1024; kk += 64) {
        __syncthreads();
        #pragma unroll
        for (int c = 0; c < 4; ++c) {
            int o = w * 4096 + c * 1024;
            int ob = o + l * 16;
            int row = ob >> 7, kb = ob & 127;
            gl_lds16((const char*)Af + ((size_t)row * 1024 + kk) * 2 + kb, (char*)ldsA + o);
            gl_lds16((const char*)Wl + ((size_t)(n0 + row) * 2048 + 1024 + kk) * 2 + kb, (char*)ldsB + o);
        }
        __syncthreads();
        #pragma unroll
        for (int ks = 0; ks < 2; ++ks) {
            bf16x8 av[4], bv[4];
            #pragma unroll
            for (int i = 0; i < 4; ++i) {
                av[i] = *(const bf16x8*)(ldsA + (wm * 64 + i * 16 + lr) * 64 + ks * 32 + lg * 8);
                bv[i] = *(const bf16x8*)(ldsB + (wn * 64 + i * 16 + lr) * 64 + ks * 32 + lg * 8);
            }
            #pragma unroll
            for (int i = 0; i < 4; ++i)
                #pragma unroll
                for (int j = 0; j < 4; ++j)
                    acc[i][j] = __builtin_amdgcn_mfma_f32_16x16x32_bf16(av[i], bv[j], acc[i][j], 0, 0, 0);
        }
    }
    float* cl = cbuf + (size_t)layer * 128 * 1024;
    #pragma unroll
    for (int i = 0; i < 4; ++i)
        #pragma unroll
        for (int j = 0; j < 4; ++j)
            #pragma unroll
            for (int q = 0; q < 4; ++q) {
                int rr = wm * 64 + i * 16 + lg * 4 + q;
                int hc = n0 + wn * 64 + j * 16 + lr;
                cl[(size_t)rr * 1024 + hc] = acc[i][j][q] + bias[hc];
            }
}

// ================= Pass 5: main fused GEMM (R9 — current best) =================
// 256x256 tile, BK=64, 16 waves (wave-tile 64x64), dbuf 2 x 64 KB, 1 blk/CU.
// One vmcnt(0)+barrier per K-tile (16 total). Swizzle x ^= ((x>>3)&0x70)
// (SQ_LDS_BANK_CONFLICT = 0 verified). XCD-affine decode (FETCH 115 MB).

__global__ __launch_bounds__(1024, 4) void fused_main(const unsigned short* __restrict__ Abf, // [32768][1024] bf16
                                                      const unsigned short* __restrict__ Wt,  // [2][1024][2048] bf16
                                                      const float* __restrict__ cbuf,         // [2][128][1024]
                                                      const float* __restrict__ W21,
                                                      const float* __restrict__ W22,
                                                      float* __restrict__ sbufp) {            // [8][32768]
    __shared__ char smem[131072];   // 2 bufs x (A 32K + B 32K)
    const int bid = blockIdx.x;
    const int xcd = bid & 7;
    const int idx = bid >> 3;                    // 0..127
    const int mtq = (idx & 3) + 4 * (idx >> 5);  // 0..15
    const int g   = (idx >> 2) & 7;              // layer*4 + nt
    const int mt  = xcd + 8 * mtq;               // 0..127
    const int layer = g >> 2;
    const int nt    = g & 3;
    const int n0 = nt * 256;

    const int tid = threadIdx.x;
    const int w = tid >> 6, l = tid & 63;
    const int wm = w >> 2, wn = w & 3;  // 4 M-quarters x 4 N-quarters (wave tile 64x64)
    const int lr = l & 15, lg = l >> 4;

    const char* Ag = (const char*)Abf + (size_t)mt * 256 * 2048;                          // row stride 2048 B
    const char* Bg = (const char*)(Wt + (size_t)layer * 1024 * 2048) + (size_t)n0 * 4096; // row stride 4096 B

    const int dloc = tid * 16;
    const int gsw  = dloc ^ ((dloc >> 3) & 0x70);
    const char* srcA = Ag + (size_t)(gsw >> 7) * 2048 + (gsw & 127);
    const char* srcB = Bg + (size_t)(gsw >> 7) * 4096 + (gsw & 127);
    const int dstT = w * 1024;   // wave-uniform LDS base (HW adds lane*16)

    const int xr = (lr & 7) << 4;
    int offA[4], offB[4];
    #pragma unroll
    for (int i = 0; i < 4; ++i) {
        offA[i] = (wm * 64 + i * 16 + lr) * 128 + ((lg * 16) ^ xr);
        offB[i] = (wn * 64 + i * 16 + lr) * 128 + ((lg * 16) ^ xr);
    }

    f32x4 acc[4][4];
    #pragma unroll
    for (int i = 0; i < 4; ++i)
        #pragma unroll
        for (int j = 0; j < 4; ++j)
            #pragma unroll
            for (int e = 0; e < 4; ++e) acc[i][j][e] = 0.f;

#define STAGE(t, bi) do {                                               \
        char* d_ = smem + (bi) * 65536;                                 \
        const char* a_ = srcA + (size_t)(t) * 128;                      \
        const char* b_ = srcB + (size_t)(t) * 128;                      \
        gl_lds16(a_,              d_ +         dstT);                   \
        gl_lds16(a_ + 128 * 2048, d_ + 16384 + dstT);                   \
        gl_lds16(b_,              d_ + 32768 + dstT);                   \
        gl_lds16(b_ + 128 * 4096, d_ + 49152 + dstT);                   \
    } while (0)

#define COMPUTE(bi) do {                                                \
        const char* Ab_ = smem + (bi) * 65536;                          \
        const char* Bb_ = Ab_ + 32768;                                  \
        bf16x8 a0_[4], b0_[4], a1_[4], b1_[4];                          \
        _Pragma("unroll")                                               \
        for (int i_ = 0; i_ < 4; ++i_) {                                \
            a0_[i_] = *(const bf16x8*)(Ab_ + offA[i_]);                 \
            b0_[i_] = *(const bf16x8*)(Bb_ + offB[i_]);                 \
            a1_[i_] = *(const bf16x8*)(Ab_ + (offA[i_] ^ 64));          \
            b1_[i_] = *(const bf16x8*)(Bb_ + (offB[i_] ^ 64));          \
        }                                                               \
        _Pragma("unroll")                                               \
        for (int i_ = 0; i_ < 4; ++i_)                                  \
            _Pragma("unroll")                                           \
            for (int j_ = 0; j_ < 4; ++j_)                              \
                acc[i_][j_] = __builtin_amdgcn_mfma_f32_16x16x32_bf16(  \
                    a0_[i_], b0_[j_], acc[i_][j_], 0, 0, 0);            \
        _Pragma("unroll")                                               \
        for (int i_ = 0; i_ < 4; ++i_)                                  \
            _Pragma("unroll")                                           \
            for (int j_ = 0; j_ < 4; ++j_)                              \
                acc[i_][j_] = __builtin_amdgcn_mfma_f32_16x16x32_bf16(  \
                    a1_[i_], b1_[j_], acc[i_][j_], 0, 0, 0);            \
    } while (0)

#define WAITBAR() do {                                                  \
        __builtin_amdgcn_sched_barrier(0);                              \
        asm volatile("s_waitcnt vmcnt(0)" ::: "memory");                \
        __builtin_amdgcn_sched_barrier(0);                              \
        __builtin_amdgcn_s_barrier();                                   \
        __builtin_amdgcn_sched_barrier(0);                              \
    } while (0)

    STAGE(0, 0);
    WAITBAR();

    for (int t = 0; t < 16; ++t) {
        const int cur = t & 1;
        if (t < 15) STAGE(t + 1, cur ^ 1);
        COMPUTE(cur);
        WAITBAR();
    }

#undef STAGE
#undef COMPUTE
#undef WAITBAR

    // ---- epilogue: z = acc + c, h = tanh(z), dot with W21/W22, reduce ----
    const float* cl = cbuf + (size_t)layer * 131072;
    const float* W2 = layer ? W22 : W21;
    float w2v[4];
    #pragma unroll
    for (int j = 0; j < 4; ++j) w2v[j] = W2[n0 + wn * 64 + j * 16 + lr];
    float* red = (float*)smem;   // [256][4]
    #pragma unroll
    for (int i = 0; i < 4; ++i) {
        #pragma unroll
        for (int q = 0; q < 4; ++q) {
            int wrow = wm * 64 + i * 16 + lg * 4 + q;    // 0..255 within M-tile
            int brow = wrow & 127;                        // b index
            float p = 0.f;
            #pragma unroll
            for (int j = 0; j < 4; ++j) {
                int col = n0 + wn * 64 + j * 16 + lr;
                float z = acc[i][j][q] + cl[(size_t)brow * 1024 + col];
                float e = __expf(2.f * z);
                p += (1.f - 2.f / (e + 1.f)) * w2v[j];
            }
            p += __shfl_xor(p, 1);
            p += __shfl_xor(p, 2);
            p += __shfl_xor(p, 4);
            p += __shfl_xor(p, 8);
            if (lr == 0) red[wrow * 4 + wn] = p;
        }
    }
    __syncthreads();
    if (tid < 256) {
        float v = red[tid * 4 + 0] + red[tid * 4 + 1] + red[tid * 4 + 2] + red[tid * 4 + 3];
        sbufp[(size_t)g * M_ROWS + (size_t)mt * 256 + tid] = v;
    }
}

// ================= ABLATION VARIANTS (write to scratch; overwritten later) =================
// Identical decode / LDS layout / grid to fused_main. Results go to sink
// (sbufp region), which the real fused_main fully rewrites afterwards.

// V1: no in-loop staging, no vmcnt — isolates LDS-read + MFMA + barrier.
__global__ __launch_bounds__(1024, 4) void abl_nostage(const unsigned short* __restrict__ Abf,
                                                       const unsigned short* __restrict__ Wt,
                                                       float* __restrict__ sink) {
    __shared__ char smem[131072];
    const int bid = blockIdx.x;
    const int tid = threadIdx.x;
    const int w = tid >> 6, l = tid & 63;
    const int wm = w >> 2, wn = w & 3;
    const int lr = l & 15, lg = l >> 4;
    const int mt = (bid & 7) + 8 * (((bid >> 3) & 3) + 4 * (bid >> 8));
    const char* Ag = (const char*)Abf + (size_t)(mt & 127) * 256 * 2048;
    const char* Bg = (const char*)Wt + (size_t)(((bid >> 5) & 3) * 256) * 4096;
    const int dloc = tid * 16;
    const int gsw  = dloc ^ ((dloc >> 3) & 0x70);
    const char* srcA = Ag + (size_t)(gsw >> 7) * 2048 + (gsw & 127);
    const char* srcB = Bg + (size_t)(gsw >> 7) * 4096 + (gsw & 127);
    const int dstT = w * 1024;
    const int xr = (lr & 7) << 4;
    int offA[4], offB[4];
    #pragma unroll
    for (int i = 0; i < 4; ++i) {
        offA[i] = (wm * 64 + i * 16 + lr) * 128 + ((lg * 16) ^ xr);
        offB[i] = (wn * 64 + i * 16 + lr) * 128 + ((lg * 16) ^ xr);
    }
    f32x4 acc[4][4];
    #pragma unroll
    for (int i = 0; i < 4; ++i)
        #pragma unroll
        for (int j = 0; j < 4; ++j)
            #pragma unroll
            for (int e = 0; e < 4; ++e) acc[i][j][e] = 0.f;

    // stage once
    gl_lds16(srcA,              smem +         dstT);
    gl_lds16(srcA + 128 * 2048, smem + 16384 + dstT);
    gl_lds16(srcB,              smem + 32768 + dstT);
    gl_lds16(srcB + 128 * 4096, smem + 49152 + dstT);
    asm volatile("s_waitcnt vmcnt(0)" ::: "memory");
    __builtin_amdgcn_s_barrier();

    for (int t = 0; t < 16; ++t) {
        const char* Ab_ = smem;
        const char* Bb_ = smem + 32768;
        bf16x8 a0_[4], b0_[4], a1_[4], b1_[4];
        #pragma unroll
        for (int i_ = 0; i_ < 4; ++i_) {
            a0_[i_] = *(const bf16x8*)(Ab_ + offA[i_]);
            b0_[i_] = *(const bf16x8*)(Bb_ + offB[i_]);
            a1_[i_] = *(const bf16x8*)(Ab_ + (offA[i_] ^ 64));
            b1_[i_] = *(const bf16x8*)(Bb_ + (offB[i_] ^ 64));
        }
        #pragma unroll
        for (int i_ = 0; i_ < 4; ++i_)
            #pragma unroll
            for (int j_ = 0; j_ < 4; ++j_)
                acc[i_][j_] = __builtin_amdgcn_mfma_f32_16x16x32_bf16(a0_[i_], b0_[j_], acc[i_][j_], 0, 0, 0);
        #pragma unroll
        for (int i_ = 0; i_ < 4; ++i_)
            #pragma unroll
            for (int j_ = 0; j_ < 4; ++j_)
                acc[i_][j_] = __builtin_amdgcn_mfma_f32_16x16x32_bf16(a1_[i_], b1_[j_], acc[i_][j_], 0, 0, 0);
        asm volatile("" ::: "memory");     // force LDS reloads each iter
        __builtin_amdgcn_s_barrier();
    }
    float s = 0.f;
    #pragma unroll
    for (int i = 0; i < 4; ++i)
        #pragma unroll
        for (int j = 0; j < 4; ++j) s += acc[i][j][0] + acc[i][j][3];
    if (tid < 256) sink[(size_t)bid * 256 + tid] = s;
}

// V2: full R9 loop minus only the vmcnt(0) drain — isolates drain cost. (Races -> scratch only.)
__global__ __launch_bounds__(1024, 4) void abl_novmcnt(const unsigned short* __restrict__ Abf,
                                                       const unsigned short* __restrict__ Wt,
                                                       float* __restrict__ sink) {
    __shared__ char smem[131072];
    const int bid = blockIdx.x;
    const int tid = threadIdx.x;
    const int w = tid >> 6, l = tid & 63;
    const int wm = w >> 2, wn = w & 3;
    const int lr = l & 15, lg = l >> 4;
    const int mt = (bid & 7) + 8 * (((bid >> 3) & 3) + 4 * (bid >> 8));
    const char* Ag = (const char*)Abf + (size_t)(mt & 127) * 256 * 2048;
    const char* Bg = (const char*)Wt + (size_t)(((bid >> 5) & 3) * 256) * 4096;
    const int dloc = tid * 16;
    const int gsw  = dloc ^ ((dloc >> 3) & 0x70);
    const char* srcA = Ag + (size_t)(gsw >> 7) * 2048 + (gsw & 127);
    const char* srcB = Bg + (size_t)(gsw >> 7) * 4096 + (gsw & 127);
    const int dstT = w * 1024;
    const int xr = (lr & 7) << 4;
    int offA[4], offB[4];
    #pragma unroll
    for (int i = 0; i < 4; ++i) {
        offA[i] = (wm * 64 + i * 16 + lr) * 128 + ((lg * 16) ^ xr);
        offB[i] = (wn * 64 + i * 16 + lr) * 128 + ((lg * 16) ^ xr);
    }
    f32x4 acc[4][4];
    #pragma unroll
    for (int i = 0; i < 4; ++i)
        #pragma unroll
        for (int j = 0; j < 4; ++j)
            #pragma unroll
            for (int e = 0; e < 4; ++e) acc[i][j][e] = 0.f;

#define STAGE2(t, bi) do {                                              \
        char* d_ = smem + (bi) * 65536;                                 \
        const char* a_ = srcA + (size_t)(t) * 128;                      \
        const char* b_ = srcB + (size_t)(t) * 128;                      \
        gl_lds16(a_,              d_ +         dstT);                   \
        gl_lds16(a_ + 128 * 2048, d_ + 16384 + dstT);                   \
        gl_lds16(b_,              d_ + 32768 + dstT);                   \
        gl_lds16(b_ + 128 * 4096, d_ + 49152 + dstT);                   \
    } while (0)

    STAGE2(0, 0);
    asm volatile("s_waitcnt vmcnt(0)" ::: "memory");
    __builtin_amdgcn_s_barrier();

    for (int t = 0; t < 16; ++t) {
        const int cur = t & 1;
        if (t < 15) STAGE2(t + 1, cur ^ 1);
        const char* Ab_ = smem + cur * 65536;
        const char* Bb_ = Ab_ + 32768;
        bf16x8 a0_[4], b0_[4], a1_[4], b1_[4];
        #pragma unroll
        for (int i_ = 0; i_ < 4; ++i_) {
            a0_[i_] = *(const bf16x8*)(Ab_ + offA[i_]);
            b0_[i_] = *(const bf16x8*)(Bb_ + offB[i_]);
            a1_[i_] = *(const bf16x8*)(Ab_ + (offA[i_] ^ 64));
            b1_[i_] = *(const bf16x8*)(Bb_ + (offB[i_] ^ 64));
        }
        #pragma unroll
        for (int i_ = 0; i_ < 4; ++i_)
            #pragma unroll
            for (int j_ = 0; j_ < 4; ++j_)
                acc[i_][j_] = __builtin_amdgcn_mfma_f32_16x16x32_bf16(a0_[i_], b0_[j_], acc[i_][j_], 0, 0, 0);
        #pragma unroll
        for (int i_ = 0; i_ < 4; ++i_)
            #pragma unroll
            for (int j_ = 0; j_ < 4; ++j_)
                acc[i_][j_] = __builtin_amdgcn_mfma_f32_16x16x32_bf16(a1_[i_], b1_[j_], acc[i_][j_], 0, 0, 0);
        asm volatile("" ::: "memory");
        __builtin_amdgcn_s_barrier();     // barrier kept, drain removed
    }
#undef STAGE2
    float s = 0.f;
    #pragma unroll
    for (int i = 0; i < 4; ++i)
        #pragma unroll
        for (int j = 0; j < 4; ++j) s += acc[i][j][0] + acc[i][j][3];
    if (tid < 256) sink[(size_t)bid * 256 + tid] = s;
}

// V3: full R9 loop with MFMA removed (asm sinks keep reads live) — isolates memory/sync path.
__global__ __launch_bounds__(1024, 4) void abl_nomfma(const unsigned short* __restrict__ Abf,
                                                      const unsigned short* __restrict__ Wt,
                                                      float* __restrict__ sink) {
    __shared__ char smem[131072];
    const int bid = blockIdx.x;
    const int tid = threadIdx.x;
    const int w = tid >> 6, l = tid & 63;
    const int wm = w >> 2, wn = w & 3;
    const int lr = l & 15, lg = l >> 4;
    const int mt = (bid & 7) + 8 * (((bid >> 3) & 3) + 4 * (bid >> 8));
    const char* Ag = (const char*)Abf + (size_t)(mt & 127) * 256 * 2048;
    const char* Bg = (const char*)Wt + (size_t)(((bid >> 5) & 3) * 256) * 4096;
    const int dloc = tid * 16;
    const int gsw  = dloc ^ ((dloc >> 3) & 0x70);
    const char* srcA = Ag + (size_t)(gsw >> 7) * 2048 + (gsw & 127);
    const char* srcB = Bg + (size_t)(gsw >> 7) * 4096 + (gsw & 127);
    const int dstT = w * 1024;
    const int xr = (lr & 7) << 4;
    int offA[4], offB[4];
    #pragma unroll
    for (int i = 0; i < 4; ++i) {
        offA[i] = (wm * 64 + i * 16 + lr) * 128 + ((lg * 16) ^ xr);
        offB[i] = (wn * 64 + i * 16 + lr) * 128 + ((lg * 16) ^ xr);
    }
    int isum = 0;

#define STAGE3(t, bi) do {                                              \
        char* d_ = smem + (bi) * 65536;                                 \
        const char* a_ = srcA + (size_t)(t) * 128;                      \
        const char* b_ = srcB + (size_t)(t) * 128;                      \
        gl_lds16(a_,              d_ +         dstT);                   \
        gl_lds16(a_ + 128 * 2048, d_ + 16384 + dstT);                   \
        gl_lds16(b_,              d_ + 32768 + dstT);                   \
        gl_lds16(b_ + 128 * 4096, d_ + 49152 + dstT);                   \
    } while (0)

    STAGE3(0, 0);
    asm volatile("s_waitcnt vmcnt(0)" ::: "memory");
    __builtin_amdgcn_s_barrier();

    for (int t = 0; t < 16; ++t) {
        const int cur = t & 1;
        if (t < 15) STAGE3(t + 1, cur ^ 1);
        const char* Ab_ = smem + cur * 65536;
        const char* Bb_ = Ab_ + 32768;
        bf16x8 a0_[4], b0_[4], a1_[4], b1_[4];
        #pragma unroll
        for (int i_ = 0; i_ < 4; ++i_) {
            a0_[i_] = *(const bf16x8*)(Ab_ + offA[i_]);
            b0_[i_] = *(const bf16x8*)(Bb_ + offB[i_]);
            a1_[i_] = *(const bf16x8*)(Ab_ + (offA[i_] ^ 64));
            b1_[i_] = *(const bf16x8*)(Bb_ + (offB[i_] ^ 64));
        }
        #pragma unroll
        for (int i_ = 0; i_ < 4; ++i_) {
            asm volatile("" :: "v"(a0_[i_]));
            asm volatile("" :: "v"(b0_[i_]));
            asm volatile("" :: "v"(a1_[i_]));
            asm volatile("" :: "v"(b1_[i_]));
        }
        isum += (int)(short)a0_[0][0] + (int)(short)b1_[3][7];
        asm volatile("s_waitcnt vmcnt(0)" ::: "memory");
        __builtin_amdgcn_s_barrier();
    }
#undef STAGE3
    if (tid < 256) sink[(size_t)bid * 256 + tid] = (float)isum;
}

// ---------------- Pass 6: softmax over s -> coef ----------------
__device__ __forceinline__ float block_max(float v, float* lds) {
    #pragma unroll
    for (int m = 32; m; m >>= 1) v = fmaxf(v, __shfl_xor(v, m));
    if ((threadIdx.x & 63) == 0) lds[threadIdx.x >> 6] = v;
    __syncthreads();
    v = fmaxf(fmaxf(lds[0], lds[1]), fmaxf(lds[2], lds[3]));
    __syncthreads();
    return v;
}
__device__ __forceinline__ float block_sum(float v, float* lds) {
    #pragma unroll
    for (int m = 32; m; m >>= 1) v += __shfl_xor(v, m);
    if ((threadIdx.x & 63) == 0) lds[threadIdx.x >> 6] = v;
    __syncthreads();
    v = lds[0] + lds[1] + lds[2] + lds[3];
    __syncthreads();
    return v;
}

__global__ __launch_bounds__(256) void coef_kernel(const float* __restrict__ sbufp,
                                                   float* __restrict__ coef) {
    __shared__ float lds[4];
    const int b = blockIdx.x, s = threadIdx.x;
    float v1 = 0.f, v2 = 0.f;
    #pragma unroll
    for (int nt = 0; nt < 4; ++nt) {
        v1 += sbufp[(size_t)nt * M_ROWS + (size_t)s * 128 + b];
        v2 += sbufp[(size_t)(4 + nt) * M_ROWS + (size_t)s * 128 + b];
    }
    float m1 = block_max(v1, lds);
    float e1 = expf(v1 - m1);
    float S1 = block_sum(e1, lds);
    float m2 = block_max(v2, lds);
    float e2 = expf(v2 - m2);
    float S2 = block_sum(e2, lds);
    coef[(size_t)s * 128 + b] = (e1 / S1 + e2 / S2) * (0.5f / (float)S_LEN);
}

// ---------------- Pass 7: out[b][d] = sum_s coef[s][b] * seq[s][b][d] ----------------
__global__ __launch_bounds__(256) void final_kernel(const float* __restrict__ seq,
                                                    const float* __restrict__ coef,
                                                    float* __restrict__ out) {
    const int b = blockIdx.x, dq = blockIdx.y;
    const int d = dq * 256 + threadIdx.x;
    float a = 0.f;
    #pragma unroll 8
    for (int s = 0; s < 256; ++s) {
        a += coef[(size_t)s * 128 + b] * seq[(size_t)(s * 128 + b) * 1024 + d];
    }
    out[(size_t)b * 1024 + d] = a;
}

extern "C" void kernel_launch(void* const* d_in, const int* in_sizes, int n_in,
                              void* d_out, int out_size, void* d_ws, size_t ws_size,
                              hipStream_t stream) {
    const float* feature1 = (const float*)d_in[0];   // [128,1024]
    const float* feature2 = (const float*)d_in[1];   // [128,1024]
    const float* seq      = (const float*)d_in[2];   // [256,128,1024]
    const float* W11      = (const float*)d_in[3];   // [2048,1024]
    const float* b11      = (const float*)d_in[4];
    const float* W12      = (const float*)d_in[5];
    const float* b12      = (const float*)d_in[6];
    const float* W21      = (const float*)d_in[7];   // [1024,1]
    const float* W22      = (const float*)d_in[9];
    float* out = (float*)d_out;

    char* ws = (char*)d_ws;
    unsigned short* Abf   = (unsigned short*)(ws + 0);                  // 67108864 B
    unsigned short* Wt    = (unsigned short*)(ws + 67108864);           //  8388608 B
    unsigned short* fbf   = (unsigned short*)(ws + 75497472);           //   524288 B
    float*          cbuf  = (float*)(ws + 76021760);                    //  1048576 B
    float*          sbufp = (float*)(ws + 77070336);                    //  1048576 B  [8][32768]
    float*          coef  = (float*)(ws + 78118912);                    //   131072 B

    convert_seq<<<2048, 256, 0, stream>>>(seq, Abf, (long)M_ROWS * 1024 / 4);
    convert_f<<<256, 256, 0, stream>>>(feature1, feature2, fbf);
    transpose_w<<<dim3(16, 32, 2), 256, 0, stream>>>(W11, W12, Wt);
    c_precompute<<<dim3(8, 2), 256, 0, stream>>>(fbf, Wt, b11, b12, cbuf);
    // --- ablation dispatches (scratch only; sbufp fully rewritten by fused_main) ---
    abl_nostage<<<1024, 1024, 0, stream>>>(Abf, Wt, sbufp);
    abl_novmcnt<<<1024, 1024, 0, stream>>>(Abf, Wt, sbufp);
    abl_nomfma<<<1024, 1024, 0, stream>>>(Abf, Wt, sbufp);
    // --- real pipeline ---
    fused_main<<<1024, 1024, 0, stream>>>(Abf, Wt, cbuf, W21, W22, sbufp);
    coef_kernel<<<128, 256, 0, stream>>>(sbufp, coef);
    final_kernel<<<dim3(128, 4), 256, 0, stream>>>(seq, coef, out);
}

// Round 14
// 251.770 us; speedup vs baseline: 1.9041x; 1.9041x over previous
//
#include <hip/hip_runtime.h>

// Problem constants
#define S_LEN 256
#define B_SZ  128
#define M_ROWS (S_LEN * B_SZ)          // 32768

typedef __attribute__((ext_vector_type(8))) short bf16x8;
typedef __attribute__((ext_vector_type(4))) float f32x4;

__device__ __forceinline__ unsigned short f2bf(float x) {
    unsigned u = __float_as_uint(x);
    unsigned r = (u + 0x7fffu + ((u >> 16) & 1u)) >> 16;   // RNE
    return (unsigned short)r;
}

__device__ __forceinline__ void gl_lds16(const void* g, void* l) {
    __builtin_amdgcn_global_load_lds(
        (const __attribute__((address_space(1))) unsigned int*)g,
        (__attribute__((address_space(3))) unsigned int*)l,
        16, 0, 0);
}

// ---------------- Pass 1: seq f32 -> bf16 ----------------
__global__ __launch_bounds__(256) void convert_seq(const float* __restrict__ in,
                                                   unsigned short* __restrict__ out,
                                                   long n4) {
    long i = (long)blockIdx.x * blockDim.x + threadIdx.x;
    long stride = (long)gridDim.x * blockDim.x;
    for (; i < n4; i += stride) {
        float4 v = ((const float4*)in)[i];
        ushort4 o;
        o.x = f2bf(v.x); o.y = f2bf(v.y); o.z = f2bf(v.z); o.w = f2bf(v.w);
        ((ushort4*)out)[i] = o;
    }
}

// ---------------- Pass 2: f1,f2 f32 -> bf16 (layer-major) ----------------
__global__ __launch_bounds__(256) void convert_f(const float* __restrict__ f1,
                                                 const float* __restrict__ f2,
                                                 unsigned short* __restrict__ out) {
    int g = blockIdx.x * 256 + threadIdx.x;            // 0..65535 float4 groups
    float4 v = (g < 32768) ? ((const float4*)f1)[g] : ((const float4*)f2)[g - 32768];
    ushort4 o;
    o.x = f2bf(v.x); o.y = f2bf(v.y); o.z = f2bf(v.z); o.w = f2bf(v.w);
    ((ushort4*)out)[g] = o;
}

// ---------------- Pass 3: W [2048][1024] f32 -> Wt [2][1024][2048] bf16 ----------------
__global__ __launch_bounds__(256) void transpose_w(const float* __restrict__ W11,
                                                   const float* __restrict__ W12,
                                                   unsigned short* __restrict__ Wt) {
    const int nt = blockIdx.x, kt = blockIdx.y, layer = blockIdx.z;
    const float* W = layer ? W12 : W11;
    __shared__ float T[64][65];
    const int c = threadIdx.x & 63, r4 = threadIdx.x >> 6;
    const int k0 = kt * 64, n0 = nt * 64;
    #pragma unroll
    for (int p = 0; p < 16; ++p) {
        int r = p * 4 + r4;
        T[r][c] = W[(size_t)(k0 + r) * 1024 + n0 + c];
    }
    __syncthreads();
    unsigned short* Wl = Wt + (size_t)layer * 1024 * 2048;
    #pragma unroll
    for (int p = 0; p < 16; ++p) {
        int n = p * 4 + r4;
        Wl[(size_t)(n0 + n) * 2048 + k0 + c] = f2bf(T[c][n]);
    }
}

// ---------------- Pass 4: c[layer][b][h] = f@W[1024:] + bias  (MFMA 128x128 tile) ----------------
__global__ __launch_bounds__(256) void c_precompute(const unsigned short* __restrict__ fbf, // [2][128][1024]
                                                    const unsigned short* __restrict__ Wt,  // [2][1024][2048]
                                                    const float* __restrict__ b11,
                                                    const float* __restrict__ b12,
                                                    float* __restrict__ cbuf) {            // [2][128][1024]
    __shared__ char smem[32768];
    unsigned short* ldsA = (unsigned short*)smem;            // [128][64]
    unsigned short* ldsB = (unsigned short*)(smem + 16384);  // [128][64]
    const int n0 = blockIdx.x * 128;
    const int layer = blockIdx.y;
    const int tid = threadIdx.x;
    const int w = tid >> 6, l = tid & 63;
    const int wm = w >> 1, wn = w & 1;
    const int lr = l & 15, lg = l >> 4;
    const unsigned short* Af = fbf + (size_t)layer * 128 * 1024;
    const unsigned short* Wl = Wt + (size_t)layer * 1024 * 2048;
    const float* bias = layer ? b12 : b11;

    f32x4 acc[4][4];
    #pragma unroll
    for (int i = 0; i < 4; ++i)
        #pragma unroll
        for (int j = 0; j < 4; ++j)
            #pragma unroll
            for (int e = 0; e < 4; ++e) acc[i][j][e] = 0.f;

    for (int kk = 0; kk < 1024; kk += 64) {
        __syncthreads();
        #pragma unroll
        for (int c = 0; c < 4; ++c) {
            int o = w * 4096 + c * 1024;
            int ob = o + l * 16;
            int row = ob >> 7, kb = ob & 127;
            gl_lds16((const char*)Af + ((size_t)row * 1024 + kk) * 2 + kb, (char*)ldsA + o);
            gl_lds16((const char*)Wl + ((size_t)(n0 + row) * 2048 + 1024 + kk) * 2 + kb, (char*)ldsB + o);
        }
        __syncthreads();
        #pragma unroll
        for (int ks = 0; ks < 2; ++ks) {
            bf16x8 av[4], bv[4];
            #pragma unroll
            for (int i = 0; i < 4; ++i) {
                av[i] = *(const bf16x8*)(ldsA + (wm * 64 + i * 16 + lr) * 64 + ks * 32 + lg * 8);
                bv[i] = *(const bf16x8*)(ldsB + (wn * 64 + i * 16 + lr) * 64 + ks * 32 + lg * 8);
            }
            #pragma unroll
            for (int i = 0; i < 4; ++i)
                #pragma unroll
                for (int j = 0; j < 4; ++j)
                    acc[i][j] = __builtin_amdgcn_mfma_f32_16x16x32_bf16(av[i], bv[j], acc[i][j], 0, 0, 0);
        }
    }
    float* cl = cbuf + (size_t)layer * 128 * 1024;
    #pragma unroll
    for (int i = 0; i < 4; ++i)
        #pragma unroll
        for (int j = 0; j < 4; ++j)
            #pragma unroll
            for (int q = 0; q < 4; ++q) {
                int rr = wm * 64 + i * 16 + lg * 4 + q;
                int hc = n0 + wn * 64 + j * 16 + lr;
                cl[(size_t)rr * 1024 + hc] = acc[i][j][q] + bias[hc];
            }
}

// ================= Pass 5: main fused GEMM =================
// 256x256 tile, BK=64, 16 waves (wave-tile 64x64), 1 blk/CU.
// LDS 160 KiB: A TRIPLE-buffered (3 x 32 KB @ 0/32768/65536) +
//              B DOUBLE-buffered (2 x 32 KB @ 98304/131072).
// Per iter t: issue B(t+1) THEN A(t+2) (B older in per-wave VMEM queue),
// COMPUTE(t), then COUNTED vmcnt(2) + barrier: forces B(t+1) and everything
// older (incl. A(t+1), issued a full iter earlier) complete; A(t+2)'s 2 loads
// stay in flight. A (L3-latency operand) gets 2-iteration prefetch depth; the
// drain tail covers only B (L2-fast). vmcnt(0) only in the 2-iter tail.
// Fully unrolled (16 iters) for static (t%3, t%2) buffer indices.
// Swizzle x ^= ((x>>3)&0x70) (SQ_LDS_BANK_CONFLICT = 0 verified since R4).
// XCD-affine decode (FETCH 115 MB verified).

__global__ __launch_bounds__(1024, 4) void fused_main(const unsigned short* __restrict__ Abf, // [32768][1024] bf16
                                                      const unsigned short* __restrict__ Wt,  // [2][1024][2048] bf16
                                                      const float* __restrict__ cbuf,         // [2][128][1024]
                                                      const float* __restrict__ W21,
                                                      const float* __restrict__ W22,
                                                      float* __restrict__ sbufp) {            // [8][32768]
    __shared__ char smem[163840];   // A: 3 x 32 KB | B: 2 x 32 KB
    const int bid = blockIdx.x;
    const int xcd = bid & 7;
    const int idx = bid >> 3;                    // 0..127
    const int mtq = (idx & 3) + 4 * (idx >> 5);  // 0..15
    const int g   = (idx >> 2) & 7;              // layer*4 + nt
    const int mt  = xcd + 8 * mtq;               // 0..127
    const int layer = g >> 2;
    const int nt    = g & 3;
    const int n0 = nt * 256;

    const int tid = threadIdx.x;
    const int w = tid >> 6, l = tid & 63;
    const int wm = w >> 2, wn = w & 3;  // 4 M-quarters x 4 N-quarters (wave tile 64x64)
    const int lr = l & 15, lg = l >> 4;

    const char* Ag = (const char*)Abf + (size_t)mt * 256 * 2048;                          // row stride 2048 B
    const char* Bg = (const char*)(Wt + (size_t)layer * 1024 * 2048) + (size_t)n0 * 4096; // row stride 4096 B

    const int dloc = tid * 16;
    const int gsw  = dloc ^ ((dloc >> 3) & 0x70);
    const char* srcA = Ag + (size_t)(gsw >> 7) * 2048 + (gsw & 127);
    const char* srcB = Bg + (size_t)(gsw >> 7) * 4096 + (gsw & 127);
    const int dstT = w * 1024;   // wave-uniform LDS base (HW adds lane*16)

    const int xr = (lr & 7) << 4;
    int offA[4], offB[4];
    #pragma unroll
    for (int i = 0; i < 4; ++i) {
        offA[i] = (wm * 64 + i * 16 + lr) * 128 + ((lg * 16) ^ xr);
        offB[i] = (wn * 64 + i * 16 + lr) * 128 + ((lg * 16) ^ xr);
    }

    f32x4 acc[4][4];
    #pragma unroll
    for (int i = 0; i < 4; ++i)
        #pragma unroll
        for (int j = 0; j < 4; ++j)
            #pragma unroll
            for (int e = 0; e < 4; ++e) acc[i][j][e] = 0.f;

#define STAGE_A(t, ta) do {                                             \
        char* d_ = smem + (ta) * 32768;                                 \
        const char* a_ = srcA + (size_t)(t) * 128;                      \
        gl_lds16(a_,          d_ +         dstT);                       \
        gl_lds16(a_ + 262144, d_ + 16384 + dstT);                       \
    } while (0)

#define STAGE_B(t, tb) do {                                             \
        char* d_ = smem + 98304 + (tb) * 32768;                         \
        const char* b_ = srcB + (size_t)(t) * 128;                      \
        gl_lds16(b_,          d_ +         dstT);                       \
        gl_lds16(b_ + 524288, d_ + 16384 + dstT);                       \
    } while (0)

#define COMPUTE(ta, tb) do {                                            \
        const char* Ab_ = smem + (ta) * 32768;                          \
        const char* Bb_ = smem + 98304 + (tb) * 32768;                  \
        bf16x8 a0_[4], b0_[4], a1_[4], b1_[4];                          \
        _Pragma("unroll")                                               \
        for (int i_ = 0; i_ < 4; ++i_) {                                \
            a0_[i_] = *(const bf16x8*)(Ab_ + offA[i_]);                 \
            b0_[i_] = *(const bf16x8*)(Bb_ + offB[i_]);                 \
            a1_[i_] = *(const bf16x8*)(Ab_ + (offA[i_] ^ 64));          \
            b1_[i_] = *(const bf16x8*)(Bb_ + (offB[i_] ^ 64));          \
        }                                                               \
        _Pragma("unroll")                                               \
        for (int i_ = 0; i_ < 4; ++i_)                                  \
            _Pragma("unroll")                                           \
            for (int j_ = 0; j_ < 4; ++j_)                              \
                acc[i_][j_] = __builtin_amdgcn_mfma_f32_16x16x32_bf16(  \
                    a0_[i_], b0_[j_], acc[i_][j_], 0, 0, 0);            \
        _Pragma("unroll")                                               \
        for (int i_ = 0; i_ < 4; ++i_)                                  \
            _Pragma("unroll")                                           \
            for (int j_ = 0; j_ < 4; ++j_)                              \
                acc[i_][j_] = __builtin_amdgcn_mfma_f32_16x16x32_bf16(  \
                    a1_[i_], b1_[j_], acc[i_][j_], 0, 0, 0);            \
    } while (0)

#define WAITBAR(n) do {                                                 \
        __builtin_amdgcn_sched_barrier(0);                              \
        asm volatile("s_waitcnt vmcnt(" #n ")" ::: "memory");           \
        __builtin_amdgcn_sched_barrier(0);                              \
        __builtin_amdgcn_s_barrier();                                   \
        __builtin_amdgcn_sched_barrier(0);                              \
    } while (0)

    // prologue: B(0)->b0, A(0)->a0, A(1)->a1; require B(0),A(0); A(1) may fly
    STAGE_B(0, 0);
    STAGE_A(0, 0);
    STAGE_A(1, 1);
    WAITBAR(2);

    // iter t: stage B(t+1)->(t+1)%2, A(t+2)->(t+2)%3; compute (t%3, t%2);
    // vmcnt(2): B(t+1)+older complete, A(t+2) in flight.
#define ITER(t, ta, tb, tb1, ta2) do {                                  \
        STAGE_B((t) + 1, tb1);                                          \
        STAGE_A((t) + 2, ta2);                                          \
        COMPUTE(ta, tb);                                                \
        WAITBAR(2);                                                     \
    } while (0)

    ITER(0, 0, 0, 1, 2);
    ITER(1, 1, 1, 0, 0);
    ITER(2, 2, 0, 1, 1);
    ITER(3, 0, 1, 0, 2);
    ITER(4, 1, 0, 1, 0);
    ITER(5, 2, 1, 0, 1);
    ITER(6, 0, 0, 1, 2);
    ITER(7, 1, 1, 0, 0);
    ITER(8, 2, 0, 1, 1);
    ITER(9, 0, 1, 0, 2);
    ITER(10, 1, 0, 1, 0);
    ITER(11, 2, 1, 0, 1);
    ITER(12, 0, 0, 1, 2);
    ITER(13, 1, 1, 0, 0);
    // t = 14: stage B(15) only; need A(15),B(15) complete before t=15
    STAGE_B(15, 1);
    COMPUTE(2, 0);
    WAITBAR(0);
    // t = 15
    COMPUTE(0, 1);
    WAITBAR(0);

#undef ITER
#undef STAGE_A
#undef STAGE_B
#undef COMPUTE
#undef WAITBAR

    // ---- epilogue: z = acc + c, h = tanh(z), dot with W21/W22, reduce ----
    const float* cl = cbuf + (size_t)layer * 131072;
    const float* W2 = layer ? W22 : W21;
    float w2v[4];
    #pragma unroll
    for (int j = 0; j < 4; ++j) w2v[j] = W2[n0 + wn * 64 + j * 16 + lr];
    float* red = (float*)smem;   // [256][4]  (final barrier above fences reuse)
    #pragma unroll
    for (int i = 0; i < 4; ++i) {
        #pragma unroll
        for (int q = 0; q < 4; ++q) {
            int wrow = wm * 64 + i * 16 + lg * 4 + q;    // 0..255 within M-tile
            int brow = wrow & 127;                        // b index
            float p = 0.f;
            #pragma unroll
            for (int j = 0; j < 4; ++j) {
                int col = n0 + wn * 64 + j * 16 + lr;
                float z = acc[i][j][q] + cl[(size_t)brow * 1024 + col];
                float e = __expf(2.f * z);
                p += (1.f - 2.f / (e + 1.f)) * w2v[j];
            }
            p += __shfl_xor(p, 1);
            p += __shfl_xor(p, 2);
            p += __shfl_xor(p, 4);
            p += __shfl_xor(p, 8);
            if (lr == 0) red[wrow * 4 + wn] = p;
        }
    }
    __syncthreads();
    if (tid < 256) {
        float v = red[tid * 4 + 0] + red[tid * 4 + 1] + red[tid * 4 + 2] + red[tid * 4 + 3];
        sbufp[(size_t)g * M_ROWS + (size_t)mt * 256 + tid] = v;
    }
}

// ---------------- Pass 6: softmax over s -> coef ----------------
__device__ __forceinline__ float block_max(float v, float* lds) {
    #pragma unroll
    for (int m = 32; m; m >>= 1) v = fmaxf(v, __shfl_xor(v, m));
    if ((threadIdx.x & 63) == 0) lds[threadIdx.x >> 6] = v;
    __syncthreads();
    v = fmaxf(fmaxf(lds[0], lds[1]), fmaxf(lds[2], lds[3]));
    __syncthreads();
    return v;
}
__device__ __forceinline__ float block_sum(float v, float* lds) {
    #pragma unroll
    for (int m = 32; m; m >>= 1) v += __shfl_xor(v, m);
    if ((threadIdx.x & 63) == 0) lds[threadIdx.x >> 6] = v;
    __syncthreads();
    v = lds[0] + lds[1] + lds[2] + lds[3];
    __syncthreads();
    return v;
}

__global__ __launch_bounds__(256) void coef_kernel(const float* __restrict__ sbufp,
                                                   float* __restrict__ coef) {
    __shared__ float lds[4];
    const int b = blockIdx.x, s = threadIdx.x;
    float v1 = 0.f, v2 = 0.f;
    #pragma unroll
    for (int nt = 0; nt < 4; ++nt) {
        v1 += sbufp[(size_t)nt * M_ROWS + (size_t)s * 128 + b];
        v2 += sbufp[(size_t)(4 + nt) * M_ROWS + (size_t)s * 128 + b];
    }
    float m1 = block_max(v1, lds);
    float e1 = expf(v1 - m1);
    float S1 = block_sum(e1, lds);
    float m2 = block_max(v2, lds);
    float e2 = expf(v2 - m2);
    float S2 = block_sum(e2, lds);
    coef[(size_t)s * 128 + b] = (e1 / S1 + e2 / S2) * (0.5f / (float)S_LEN);
}

// ---------------- Pass 7: out[b][d] = sum_s coef[s][b] * seq[s][b][d] ----------------
// Atomic-free: each thread owns one output element, loops all 256 s.
__global__ __launch_bounds__(256) void final_kernel(const float* __restrict__ seq,
                                                    const float* __restrict__ coef,
                                                    float* __restrict__ out) {
    const int b = blockIdx.x, dq = blockIdx.y;
    const int d = dq * 256 + threadIdx.x;
    float a = 0.f;
    #pragma unroll 8
    for (int s = 0; s < 256; ++s) {
        a += coef[(size_t)s * 128 + b] * seq[(size_t)(s * 128 + b) * 1024 + d];
    }
    out[(size_t)b * 1024 + d] = a;
}

extern "C" void kernel_launch(void* const* d_in, const int* in_sizes, int n_in,
                              void* d_out, int out_size, void* d_ws, size_t ws_size,
                              hipStream_t stream) {
    const float* feature1 = (const float*)d_in[0];   // [128,1024]
    const float* feature2 = (const float*)d_in[1];   // [128,1024]
    const float* seq      = (const float*)d_in[2];   // [256,128,1024]
    const float* W11      = (const float*)d_in[3];   // [2048,1024]
    const float* b11      = (const float*)d_in[4];
    const float* W12      = (const float*)d_in[5];
    const float* b12      = (const float*)d_in[6];
    const float* W21      = (const float*)d_in[7];   // [1024,1]
    const float* W22      = (const float*)d_in[9];
    float* out = (float*)d_out;

    char* ws = (char*)d_ws;
    unsigned short* Abf   = (unsigned short*)(ws + 0);                  // 67108864 B
    unsigned short* Wt    = (unsigned short*)(ws + 67108864);           //  8388608 B
    unsigned short* fbf   = (unsigned short*)(ws + 75497472);           //   524288 B
    float*          cbuf  = (float*)(ws + 76021760);                    //  1048576 B
    float*          sbufp = (float*)(ws + 77070336);                    //  1048576 B  [8][32768]
    float*          coef  = (float*)(ws + 78118912);                    //   131072 B

    convert_seq<<<2048, 256, 0, stream>>>(seq, Abf, (long)M_ROWS * 1024 / 4);
    convert_f<<<256, 256, 0, stream>>>(feature1, feature2, fbf);
    transpose_w<<<dim3(16, 32, 2), 256, 0, stream>>>(W11, W12, Wt);
    c_precompute<<<dim3(8, 2), 256, 0, stream>>>(fbf, Wt, b11, b12, cbuf);
    fused_main<<<1024, 1024, 0, stream>>>(Abf, Wt, cbuf, W21, W22, sbufp);
    coef_kernel<<<128, 256, 0, stream>>>(sbufp, coef);
    final_kernel<<<dim3(128, 4), 256, 0, stream>>>(seq, coef, out);
}

// Round 15
// 232.040 us; speedup vs baseline: 2.0660x; 1.0850x over previous
//
#include <hip/hip_runtime.h>

// Problem constants
#define S_LEN 256
#define B_SZ  128
#define M_ROWS (S_LEN * B_SZ)          // 32768

typedef __attribute__((ext_vector_type(8))) short bf16x8;
typedef __attribute__((ext_vector_type(4))) float f32x4;

__device__ __forceinline__ unsigned short f2bf(float x) {
    unsigned u = __float_as_uint(x);
    unsigned r = (u + 0x7fffu + ((u >> 16) & 1u)) >> 16;   // RNE
    return (unsigned short)r;
}

__device__ __forceinline__ void gl_lds16(const void* g, void* l) {
    __builtin_amdgcn_global_load_lds(
        (const __attribute__((address_space(1))) unsigned int*)g,
        (__attribute__((address_space(3))) unsigned int*)l,
        16, 0, 0);
}

// ---------------- Pass 1: seq f32 -> bf16 ----------------
__global__ __launch_bounds__(256) void convert_seq(const float* __restrict__ in,
                                                   unsigned short* __restrict__ out,
                                                   long n4) {
    long i = (long)blockIdx.x * blockDim.x + threadIdx.x;
    long stride = (long)gridDim.x * blockDim.x;
    for (; i < n4; i += stride) {
        float4 v = ((const float4*)in)[i];
        ushort4 o;
        o.x = f2bf(v.x); o.y = f2bf(v.y); o.z = f2bf(v.z); o.w = f2bf(v.w);
        ((ushort4*)out)[i] = o;
    }
}

// ---------------- Pass 2: f1,f2 f32 -> bf16 (layer-major) ----------------
__global__ __launch_bounds__(256) void convert_f(const float* __restrict__ f1,
                                                 const float* __restrict__ f2,
                                                 unsigned short* __restrict__ out) {
    int g = blockIdx.x * 256 + threadIdx.x;            // 0..65535 float4 groups
    float4 v = (g < 32768) ? ((const float4*)f1)[g] : ((const float4*)f2)[g - 32768];
    ushort4 o;
    o.x = f2bf(v.x); o.y = f2bf(v.y); o.z = f2bf(v.z); o.w = f2bf(v.w);
    ((ushort4*)out)[g] = o;
}

// ---------------- Pass 3: W [2048][1024] f32 -> Wt [2][1024][2048] bf16 ----------------
__global__ __launch_bounds__(256) void transpose_w(const float* __restrict__ W11,
                                                   const float* __restrict__ W12,
                                                   unsigned short* __restrict__ Wt) {
    const int nt = blockIdx.x, kt = blockIdx.y, layer = blockIdx.z;
    const float* W = layer ? W12 : W11;
    __shared__ float T[64][65];
    const int c = threadIdx.x & 63, r4 = threadIdx.x >> 6;
    const int k0 = kt * 64, n0 = nt * 64;
    #pragma unroll
    for (int p = 0; p < 16; ++p) {
        int r = p * 4 + r4;
        T[r][c] = W[(size_t)(k0 + r) * 1024 + n0 + c];
    }
    __syncthreads();
    unsigned short* Wl = Wt + (size_t)layer * 1024 * 2048;
    #pragma unroll
    for (int p = 0; p < 16; ++p) {
        int n = p * 4 + r4;
        Wl[(size_t)(n0 + n) * 2048 + k0 + c] = f2bf(T[c][n]);
    }
}

// ---------------- Pass 4: c[layer][b][h] = f@W[1024:] + bias  (MFMA 128x128 tile) ----------------
__global__ __launch_bounds__(256) void c_precompute(const unsigned short* __restrict__ fbf, // [2][128][1024]
                                                    const unsigned short* __restrict__ Wt,  // [2][1024][2048]
                                                    const float* __restrict__ b11,
                                                    const float* __restrict__ b12,
                                                    float* __restrict__ cbuf) {            // [2][128][1024]
    __shared__ char smem[32768];
    unsigned short* ldsA = (unsigned short*)smem;            // [128][64]
    unsigned short* ldsB = (unsigned short*)(smem + 16384);  // [128][64]
    const int n0 = blockIdx.x * 128;
    const int layer = blockIdx.y;
    const int tid = threadIdx.x;
    const int w = tid >> 6, l = tid & 63;
    const int wm = w >> 1, wn = w & 1;
    const int lr = l & 15, lg = l >> 4;
    const unsigned short* Af = fbf + (size_t)layer * 128 * 1024;
    const unsigned short* Wl = Wt + (size_t)layer * 1024 * 2048;
    const float* bias = layer ? b12 : b11;

    f32x4 acc[4][4];
    #pragma unroll
    for (int i = 0; i < 4; ++i)
        #pragma unroll
        for (int j = 0; j < 4; ++j)
            #pragma unroll
            for (int e = 0; e < 4; ++e) acc[i][j][e] = 0.f;

    for (int kk = 0; kk < 1024; kk += 64) {
        __syncthreads();
        #pragma unroll
        for (int c = 0; c < 4; ++c) {
            int o = w * 4096 + c * 1024;
            int ob = o + l * 16;
            int row = ob >> 7, kb = ob & 127;
            gl_lds16((const char*)Af + ((size_t)row * 1024 + kk) * 2 + kb, (char*)ldsA + o);
            gl_lds16((const char*)Wl + ((size_t)(n0 + row) * 2048 + 1024 + kk) * 2 + kb, (char*)ldsB + o);
        }
        __syncthreads();
        #pragma unroll
        for (int ks = 0; ks < 2; ++ks) {
            bf16x8 av[4], bv[4];
            #pragma unroll
            for (int i = 0; i < 4; ++i) {
                av[i] = *(const bf16x8*)(ldsA + (wm * 64 + i * 16 + lr) * 64 + ks * 32 + lg * 8);
                bv[i] = *(const bf16x8*)(ldsB + (wn * 64 + i * 16 + lr) * 64 + ks * 32 + lg * 8);
            }
            #pragma unroll
            for (int i = 0; i < 4; ++i)
                #pragma unroll
                for (int j = 0; j < 4; ++j)
                    acc[i][j] = __builtin_amdgcn_mfma_f32_16x16x32_bf16(av[i], bv[j], acc[i][j], 0, 0, 0);
        }
    }
    float* cl = cbuf + (size_t)layer * 128 * 1024;
    #pragma unroll
    for (int i = 0; i < 4; ++i)
        #pragma unroll
        for (int j = 0; j < 4; ++j)
            #pragma unroll
            for (int q = 0; q < 4; ++q) {
                int rr = wm * 64 + i * 16 + lg * 4 + q;
                int hc = n0 + wn * 64 + j * 16 + lr;
                cl[(size_t)rr * 1024 + hc] = acc[i][j][q] + bias[hc];
            }
}

// ================= Pass 5: main fused GEMM (R9 structure — measured best) =================
// 256x256 tile, BK=64, 16 waves (wave-tile 64x64), dbuf 2 x 64 KB, 1 blk/CU.
// One vmcnt(0)+barrier per K-tile (16 total). Swizzle x ^= ((x>>3)&0x70)
// (SQ_LDS_BANK_CONFLICT = 0 verified). XCD-affine decode (FETCH 115 MB).
// Cycle model (validated R13 ablations): per-tile = LDS burst (~3765 cyc:
// 256 KB reads + 64 KB staged writes @ ~85 B/cyc) + MFMA (~2480 cyc) mostly
// serial, because 1024-thread blocks cap VGPR at 128 (acc=64) so fragment
// prefetch across the read/MFMA boundary cannot be held in registers.
// All 7 alternative structures measured worse (R3/R6/R7/R8/R10/R11/R12/R14).
// COMPUTE loads grouped ks0-first so the compiler's lgkmcnt schedule can
// start ks0 MFMAs at the half-burst point where pressure allows.

__global__ __launch_bounds__(1024, 4) void fused_main(const unsigned short* __restrict__ Abf, // [32768][1024] bf16
                                                      const unsigned short* __restrict__ Wt,  // [2][1024][2048] bf16
                                                      const float* __restrict__ cbuf,         // [2][128][1024]
                                                      const float* __restrict__ W21,
                                                      const float* __restrict__ W22,
                                                      float* __restrict__ sbufp) {            // [8][32768]
    __shared__ char smem[131072];   // 2 bufs x (A 32K + B 32K)
    const int bid = blockIdx.x;
    const int xcd = bid & 7;
    const int idx = bid >> 3;                    // 0..127
    const int mtq = (idx & 3) + 4 * (idx >> 5);  // 0..15
    const int g   = (idx >> 2) & 7;              // layer*4 + nt
    const int mt  = xcd + 8 * mtq;               // 0..127
    const int layer = g >> 2;
    const int nt    = g & 3;
    const int n0 = nt * 256;

    const int tid = threadIdx.x;
    const int w = tid >> 6, l = tid & 63;
    const int wm = w >> 2, wn = w & 3;  // 4 M-quarters x 4 N-quarters (wave tile 64x64)
    const int lr = l & 15, lg = l >> 4;

    const char* Ag = (const char*)Abf + (size_t)mt * 256 * 2048;                          // row stride 2048 B
    const char* Bg = (const char*)(Wt + (size_t)layer * 1024 * 2048) + (size_t)n0 * 4096; // row stride 4096 B

    const int dloc = tid * 16;
    const int gsw  = dloc ^ ((dloc >> 3) & 0x70);
    const char* srcA = Ag + (size_t)(gsw >> 7) * 2048 + (gsw & 127);
    const char* srcB = Bg + (size_t)(gsw >> 7) * 4096 + (gsw & 127);
    const int dstT = w * 1024;   // wave-uniform LDS base (HW adds lane*16)

    const int xr = (lr & 7) << 4;
    int offA[4], offB[4];
    #pragma unroll
    for (int i = 0; i < 4; ++i) {
        offA[i] = (wm * 64 + i * 16 + lr) * 128 + ((lg * 16) ^ xr);
        offB[i] = (wn * 64 + i * 16 + lr) * 128 + ((lg * 16) ^ xr);
    }

    f32x4 acc[4][4];
    #pragma unroll
    for (int i = 0; i < 4; ++i)
        #pragma unroll
        for (int j = 0; j < 4; ++j)
            #pragma unroll
            for (int e = 0; e < 4; ++e) acc[i][j][e] = 0.f;

#define STAGE(t, bi) do {                                               \
        char* d_ = smem + (bi) * 65536;                                 \
        const char* a_ = srcA + (size_t)(t) * 128;                      \
        const char* b_ = srcB + (size_t)(t) * 128;                      \
        gl_lds16(a_,              d_ +         dstT);                   \
        gl_lds16(a_ + 128 * 2048, d_ + 16384 + dstT);                   \
        gl_lds16(b_,              d_ + 32768 + dstT);                   \
        gl_lds16(b_ + 128 * 4096, d_ + 49152 + dstT);                   \
    } while (0)

#define COMPUTE(bi) do {                                                \
        const char* Ab_ = smem + (bi) * 65536;                          \
        const char* Bb_ = Ab_ + 32768;                                  \
        bf16x8 a0_[4], b0_[4], a1_[4], b1_[4];                          \
        _Pragma("unroll")                                               \
        for (int i_ = 0; i_ < 4; ++i_) {                                \
            a0_[i_] = *(const bf16x8*)(Ab_ + offA[i_]);                 \
            b0_[i_] = *(const bf16x8*)(Bb_ + offB[i_]);                 \
        }                                                               \
        _Pragma("unroll")                                               \
        for (int i_ = 0; i_ < 4; ++i_) {                                \
            a1_[i_] = *(const bf16x8*)(Ab_ + (offA[i_] ^ 64));          \
            b1_[i_] = *(const bf16x8*)(Bb_ + (offB[i_] ^ 64));          \
        }                                                               \
        _Pragma("unroll")                                               \
        for (int i_ = 0; i_ < 4; ++i_)                                  \
            _Pragma("unroll")                                           \
            for (int j_ = 0; j_ < 4; ++j_)                              \
                acc[i_][j_] = __builtin_amdgcn_mfma_f32_16x16x32_bf16(  \
                    a0_[i_], b0_[j_], acc[i_][j_], 0, 0, 0);            \
        _Pragma("unroll")                                               \
        for (int i_ = 0; i_ < 4; ++i_)                                  \
            _Pragma("unroll")                                           \
            for (int j_ = 0; j_ < 4; ++j_)                              \
                acc[i_][j_] = __builtin_amdgcn_mfma_f32_16x16x32_bf16(  \
                    a1_[i_], b1_[j_], acc[i_][j_], 0, 0, 0);            \
    } while (0)

#define WAITBAR() do {                                                  \
        __builtin_amdgcn_sched_barrier(0);                              \
        asm volatile("s_waitcnt vmcnt(0)" ::: "memory");                \
        __builtin_amdgcn_sched_barrier(0);                              \
        __builtin_amdgcn_s_barrier();                                   \
        __builtin_amdgcn_sched_barrier(0);                              \
    } while (0)

    STAGE(0, 0);
    WAITBAR();

    for (int t = 0; t < 16; ++t) {
        const int cur = t & 1;
        if (t < 15) STAGE(t + 1, cur ^ 1);
        COMPUTE(cur);
        WAITBAR();
    }

#undef STAGE
#undef COMPUTE
#undef WAITBAR

    // ---- epilogue: z = acc + c, h = tanh(z), dot with W21/W22, reduce ----
    const float* cl = cbuf + (size_t)layer * 131072;
    const float* W2 = layer ? W22 : W21;
    float w2v[4];
    #pragma unroll
    for (int j = 0; j < 4; ++j) w2v[j] = W2[n0 + wn * 64 + j * 16 + lr];
    float* red = (float*)smem;   // [256][4]
    #pragma unroll
    for (int i = 0; i < 4; ++i) {
        #pragma unroll
        for (int q = 0; q < 4; ++q) {
            int wrow = wm * 64 + i * 16 + lg * 4 + q;    // 0..255 within M-tile
            int brow = wrow & 127;                        // b index
            float p = 0.f;
            #pragma unroll
            for (int j = 0; j < 4; ++j) {
                int col = n0 + wn * 64 + j * 16 + lr;
                float z = acc[i][j][q] + cl[(size_t)brow * 1024 + col];
                float e = __expf(2.f * z);
                p += (1.f - 2.f / (e + 1.f)) * w2v[j];
            }
            p += __shfl_xor(p, 1);
            p += __shfl_xor(p, 2);
            p += __shfl_xor(p, 4);
            p += __shfl_xor(p, 8);
            if (lr == 0) red[wrow * 4 + wn] = p;
        }
    }
    __syncthreads();
    if (tid < 256) {
        float v = red[tid * 4 + 0] + red[tid * 4 + 1] + red[tid * 4 + 2] + red[tid * 4 + 3];
        sbufp[(size_t)g * M_ROWS + (size_t)mt * 256 + tid] = v;
    }
}

// ---------------- Pass 6: softmax over s -> coef ----------------
__device__ __forceinline__ float block_max(float v, float* lds) {
    #pragma unroll
    for (int m = 32; m; m >>= 1) v = fmaxf(v, __shfl_xor(v, m));
    if ((threadIdx.x & 63) == 0) lds[threadIdx.x >> 6] = v;
    __syncthreads();
    v = fmaxf(fmaxf(lds[0], lds[1]), fmaxf(lds[2], lds[3]));
    __syncthreads();
    return v;
}
__device__ __forceinline__ float block_sum(float v, float* lds) {
    #pragma unroll
    for (int m = 32; m; m >>= 1) v += __shfl_xor(v, m);
    if ((threadIdx.x & 63) == 0) lds[threadIdx.x >> 6] = v;
    __syncthreads();
    v = lds[0] + lds[1] + lds[2] + lds[3];
    __syncthreads();
    return v;
}

__global__ __launch_bounds__(256) void coef_kernel(const float* __restrict__ sbufp,
                                                   float* __restrict__ coef) {
    __shared__ float lds[4];
    const int b = blockIdx.x, s = threadIdx.x;
    float v1 = 0.f, v2 = 0.f;
    #pragma unroll
    for (int nt = 0; nt < 4; ++nt) {
        v1 += sbufp[(size_t)nt * M_ROWS + (size_t)s * 128 + b];
        v2 += sbufp[(size_t)(4 + nt) * M_ROWS + (size_t)s * 128 + b];
    }
    float m1 = block_max(v1, lds);
    float e1 = expf(v1 - m1);
    float S1 = block_sum(e1, lds);
    float m2 = block_max(v2, lds);
    float e2 = expf(v2 - m2);
    float S2 = block_sum(e2, lds);
    coef[(size_t)s * 128 + b] = (e1 / S1 + e2 / S2) * (0.5f / (float)S_LEN);
}

// ---------------- Pass 7: out[b][d] = sum_s coef[s][b] * seq[s][b][d] ----------------
// Atomic-free: each thread owns one output element, loops all 256 s.
__global__ __launch_bounds__(256) void final_kernel(const float* __restrict__ seq,
                                                    const float* __restrict__ coef,
                                                    float* __restrict__ out) {
    const int b = blockIdx.x, dq = blockIdx.y;
    const int d = dq * 256 + threadIdx.x;
    float a = 0.f;
    #pragma unroll 8
    for (int s = 0; s < 256; ++s) {
        a += coef[(size_t)s * 128 + b] * seq[(size_t)(s * 128 + b) * 1024 + d];
    }
    out[(size_t)b * 1024 + d] = a;
}

extern "C" void kernel_launch(void* const* d_in, const int* in_sizes, int n_in,
                              void* d_out, int out_size, void* d_ws, size_t ws_size,
                              hipStream_t stream) {
    const float* feature1 = (const float*)d_in[0];   // [128,1024]
    const float* feature2 = (const float*)d_in[1];   // [128,1024]
    const float* seq      = (const float*)d_in[2];   // [256,128,1024]
    const float* W11      = (const float*)d_in[3];   // [2048,1024]
    const float* b11      = (const float*)d_in[4];
    const float* W12      = (const float*)d_in[5];
    const float* b12      = (const float*)d_in[6];
    const float* W21      = (const float*)d_in[7];   // [1024,1]
    const float* W22      = (const float*)d_in[9];
    float* out = (float*)d_out;

    char* ws = (char*)d_ws;
    unsigned short* Abf   = (unsigned short*)(ws + 0);                  // 67108864 B
    unsigned short* Wt    = (unsigned short*)(ws + 67108864);           //  8388608 B
    unsigned short* fbf   = (unsigned short*)(ws + 75497472);           //   524288 B
    float*          cbuf  = (float*)(ws + 76021760);                    //  1048576 B
    float*          sbufp = (float*)(ws + 77070336);                    //  1048576 B  [8][32768]
    float*          coef  = (float*)(ws + 78118912);                    //   131072 B

    convert_seq<<<2048, 256, 0, stream>>>(seq, Abf, (long)M_ROWS * 1024 / 4);
    convert_f<<<256, 256, 0, stream>>>(feature1, feature2, fbf);
    transpose_w<<<dim3(16, 32, 2), 256, 0, stream>>>(W11, W12, Wt);
    c_precompute<<<dim3(8, 2), 256, 0, stream>>>(fbf, Wt, b11, b12, cbuf);
    fused_main<<<1024, 1024, 0, stream>>>(Abf, Wt, cbuf, W21, W22, sbufp);
    coef_kernel<<<128, 256, 0, stream>>>(sbufp, coef);
    final_kernel<<<dim3(128, 4), 256, 0, stream>>>(seq, coef, out);
}